// Round 1
// baseline (1580.126 us; speedup 1.0000x reference)
//
#include <hip/hip_runtime.h>
#include <hip/hip_bf16.h>

#define B_ 256
#define N_ 4096
#define D_ 64
#define K_ 16
#define EPS_ 1e-8f
#define LN_EPS_ 1e-5f

__device__ __forceinline__ float wsum64(float v) {
  v += __shfl_xor(v, 1);
  v += __shfl_xor(v, 2);
  v += __shfl_xor(v, 4);
  v += __shfl_xor(v, 8);
  v += __shfl_xor(v, 16);
  v += __shfl_xor(v, 32);
  return v;
}

__device__ __forceinline__ float rsum16(float v) {
  v += __shfl_xor(v, 1);
  v += __shfl_xor(v, 2);
  v += __shfl_xor(v, 4);
  v += __shfl_xor(v, 8);
  return v;
}

__device__ __forceinline__ float rmax16(float v) {
  v = fmaxf(v, __shfl_xor(v, 1));
  v = fmaxf(v, __shfl_xor(v, 2));
  v = fmaxf(v, __shfl_xor(v, 4));
  v = fmaxf(v, __shfl_xor(v, 8));
  return v;
}

// MODE 0: accumulate U,S and xsum (first pass); MODE 1: accumulate U,S; MODE 2: final, write attn.
template<int MODE>
__global__ __launch_bounds__(256)
void attend_kernel(const float* __restrict__ inputs,
                   const float* __restrict__ g_in, const float* __restrict__ b_in,
                   const float* __restrict__ q2w, const float* __restrict__ qcw,
                   float* __restrict__ U, float* __restrict__ S, float* __restrict__ xs,
                   float* __restrict__ attn_out)
{
  const int b = blockIdx.y;
  const int chunk = blockIdx.x;             // 4 chunks of 1024 rows
  const int wave = threadIdx.x >> 6;
  const int lane = threadIdx.x & 63;
  const int k = lane & 15;
  const int qq = lane >> 4;

  __shared__ float xshB[4][4][64];          // [wave][row-in-group][d]
  __shared__ float red[16 * 256];
  __shared__ float redS[4 * 16];
  __shared__ float redX[4][64];

  // q' = q @ Wk for this batch: lane (k,qq) keeps q2[k][qq*16 .. qq*16+15]
  float q2r[16];
#pragma unroll
  for (int i = 0; i < 16; ++i) q2r[i] = q2w[b * 1024 + k * 64 + qq * 16 + i];
  const float qcv = qcw[b * 16 + k];        // q . bk
  const float4 gi4 = ((const float4*)g_in)[k];  // k == lane&15 indexes d-quads for LN
  const float4 bi4 = ((const float4*)b_in)[k];
  const float scale = 0.125f;               // D^-0.5

  float Uacc[16];
#pragma unroll
  for (int i = 0; i < 16; ++i) Uacc[i] = 0.f;
  float Sacc = 0.f;
  float xsacc[16];
#pragma unroll
  for (int i = 0; i < 16; ++i) xsacc[i] = 0.f;

  const int rowbase = chunk * 1024 + wave * 256;      // 256 rows per wave
  const float4* __restrict__ ip4 = (const float4*)(inputs + ((size_t)b * N_ + rowbase) * D_);

  float4 cur = ip4[lane];
  for (int it = 0; it < 64; ++it) {                   // 4 rows per iteration
    const int itn = (it + 1) & 63;
    float4 nxt = ip4[itn * 64 + lane];                // prefetch (wraps harmlessly)

    // ---- LayerNorm of 4 rows: lane holds row (lane>>4), dims (lane&15)*4 .. +3
    float s = cur.x + cur.y + cur.z + cur.w;
    float m = rsum16(s) * (1.f / 64.f);
    float dx = cur.x - m, dy = cur.y - m, dz = cur.z - m, dw = cur.w - m;
    float v2 = dx * dx + dy * dy + dz * dz + dw * dw;
    float var = rsum16(v2) * (1.f / 64.f);
    float rs = rsqrtf(var + LN_EPS_);
    float4 xv;
    xv.x = dx * rs * gi4.x + bi4.x;
    xv.y = dy * rs * gi4.y + bi4.y;
    xv.z = dz * rs * gi4.z + bi4.z;
    xv.w = dw * rs * gi4.w + bi4.w;
    ((float4*)&xshB[wave][qq][k * 4])[0] = xv;        // row = lane>>4 == qq, dcol = (lane&15)*4

#pragma unroll
    for (int rr = 0; rr < 4; ++rr) {
      const float4* xp = (const float4*)(&xshB[wave][rr][qq * 16]);
      float4 a0 = xp[0], a1 = xp[1], a2 = xp[2], a3 = xp[3];
      float xr[16] = {a0.x, a0.y, a0.z, a0.w, a1.x, a1.y, a1.z, a1.w,
                      a2.x, a2.y, a2.z, a2.w, a3.x, a3.y, a3.z, a3.w};
      // logit partial over this lane's 16 dims
      float lg = 0.f;
#pragma unroll
      for (int i = 0; i < 16; ++i) lg += q2r[i] * xr[i];
      lg += __shfl_xor(lg, 16);
      lg += __shfl_xor(lg, 32);
      lg = (lg + qcv) * scale;
      // softmax over 16 slots (lanes differing in bits 0..3)
      float mx = rmax16(lg);
      float e = __expf(lg - mx);
      float ssum = rsum16(e);
      float p = e / ssum;

      if (MODE == 2) {
        if (qq == 0) attn_out[((size_t)b * 16 + k) * N_ + rowbase + it * 4 + rr] = p;
      } else {
#pragma unroll
        for (int i = 0; i < 16; ++i) Uacc[i] += p * xr[i];
        Sacc += p;
        if (MODE == 0) {
#pragma unroll
          for (int i = 0; i < 16; ++i) xsacc[i] += xr[i];
        }
      }
    }
    cur = nxt;
  }

  if (MODE == 2) return;

  // ---- block reduction + atomics
#pragma unroll
  for (int i = 0; i < 16; ++i) red[i * 256 + wave * 64 + lane] = Uacc[i];
  if (qq == 0) redS[wave * 16 + k] = Sacc;
  if (k == 0) {
#pragma unroll
    for (int i = 0; i < 16; ++i) redX[wave][qq * 16 + i] = xsacc[i];
  }
  __syncthreads();

#pragma unroll
  for (int ii = 0; ii < 4; ++ii) {
    int i = wave * 4 + ii;
    float sum = red[i * 256 + 0 * 64 + lane] + red[i * 256 + 1 * 64 + lane] +
                red[i * 256 + 2 * 64 + lane] + red[i * 256 + 3 * 64 + lane];
    atomicAdd(&U[b * 1024 + (lane & 15) * 64 + (lane >> 4) * 16 + i], sum);
  }
  const int tid = threadIdx.x;
  if (tid < 16) {
    float s4 = redS[tid] + redS[16 + tid] + redS[32 + tid] + redS[48 + tid];
    atomicAdd(&S[b * 16 + tid], s4);
  }
  if (MODE == 0 && tid < 64) {
    float s4 = redX[0][tid] + redX[1][tid] + redX[2][tid] + redX[3][tid];
    atomicAdd(&xs[b * 64 + tid], s4);
  }
}

// Per-batch slot update (GRU + MLP) and q' recompute. iter==0: init slots from noise.
__global__ __launch_bounds__(256)
void mid_kernel(int iter,
                const float* __restrict__ noise, const float* __restrict__ mu,
                const float* __restrict__ logvar,
                const float* __restrict__ wq, const float* __restrict__ bq,
                const float* __restrict__ wk, const float* __restrict__ bk,
                const float* __restrict__ wv, const float* __restrict__ bv,
                const float* __restrict__ w_ih, const float* __restrict__ w_hh,
                const float* __restrict__ b_ih, const float* __restrict__ b_hh,
                const float* __restrict__ g_sl, const float* __restrict__ b_sl,
                const float* __restrict__ g_mlp, const float* __restrict__ b_mlp,
                const float* __restrict__ w1, const float* __restrict__ b1,
                const float* __restrict__ w2, const float* __restrict__ b2,
                float* __restrict__ slots_ws, float* __restrict__ q2w, float* __restrict__ qcw,
                const float* __restrict__ U, const float* __restrict__ S,
                const float* __restrict__ xs, float* __restrict__ out_slots)
{
  const int b = blockIdx.x;
  const int tid = threadIdx.x;
  __shared__ float sl[1024];
  __shared__ float snew[1024];
  __shared__ float updx[1024];
  __shared__ float upds[1024];
  __shared__ float gx[3072];
  __shared__ float gh[3072];
  __shared__ float hh[1024];
  __shared__ float t1[2048];
  __shared__ float qv[1024];

  if (iter == 0) {
    for (int idx = tid; idx < 1024; idx += 256) {
      int d = idx & 63;
      snew[idx] = mu[d] + expf(0.5f * logvar[d]) * noise[(size_t)b * 1024 + idx];
    }
    __syncthreads();
  } else {
    for (int idx = tid; idx < 1024; idx += 256) sl[idx] = slots_ws[b * 1024 + idx];
    for (int idx = tid; idx < 1024; idx += 256) {
      int kk = idx >> 6, e = idx & 63;
      float denom = S[b * 16 + kk] + (float)N_ * EPS_;
      updx[idx] = (U[b * 1024 + idx] + EPS_ * xs[b * 64 + e]) / denom;
    }
    __syncthreads();
    // upd = updx @ Wv^T + bv
    for (int idx = tid; idx < 1024; idx += 256) {
      int kk = idx >> 6, d = idx & 63;
      float acc = bv[d];
      for (int e = 0; e < 64; ++e) acc += updx[kk * 64 + e] * wv[d * 64 + e];
      upds[idx] = acc;
    }
    __syncthreads();
    // GRU gate pre-activations
    for (int idx = tid; idx < 3072; idx += 256) {
      int kk = idx / 192, j = idx % 192;
      float ax = b_ih[j], ah = b_hh[j];
      for (int d = 0; d < 64; ++d) {
        ax += upds[kk * 64 + d] * w_ih[j * 64 + d];
        ah += sl[kk * 64 + d] * w_hh[j * 64 + d];
      }
      gx[idx] = ax;
      gh[idx] = ah;
    }
    __syncthreads();
    for (int idx = tid; idx < 1024; idx += 256) {
      int kk = idx >> 6, d = idx & 63;
      float xr_ = gx[kk * 192 + d], xz_ = gx[kk * 192 + 64 + d], xn_ = gx[kk * 192 + 128 + d];
      float hr_ = gh[kk * 192 + d], hz_ = gh[kk * 192 + 64 + d], hn_ = gh[kk * 192 + 128 + d];
      float r_ = 1.f / (1.f + expf(-(xr_ + hr_)));
      float z_ = 1.f / (1.f + expf(-(xz_ + hz_)));
      float n_ = tanhf(xn_ + r_ * hn_);
      snew[idx] = (1.f - z_) * n_ + z_ * sl[idx];
    }
    __syncthreads();
    // h = LN(snew, g_mlp, b_mlp)
    {
      int wv_ = tid >> 6, lane = tid & 63;
      for (int kk = wv_; kk < 16; kk += 4) {
        float v = snew[kk * 64 + lane];
        float m = wsum64(v) * (1.f / 64.f);
        float dd = v - m;
        float var = wsum64(dd * dd) * (1.f / 64.f);
        hh[kk * 64 + lane] = dd * rsqrtf(var + LN_EPS_) * g_mlp[lane] + b_mlp[lane];
      }
    }
    __syncthreads();
    for (int idx = tid; idx < 2048; idx += 256) {
      int kk = idx >> 7, j = idx & 127;
      float acc = b1[j];
      for (int d = 0; d < 64; ++d) acc += hh[kk * 64 + d] * w1[j * 64 + d];
      t1[idx] = fmaxf(acc, 0.f);
    }
    __syncthreads();
    for (int idx = tid; idx < 1024; idx += 256) {
      int kk = idx >> 6, d = idx & 63;
      float acc = b2[d];
      for (int j = 0; j < 128; ++j) acc += t1[kk * 128 + j] * w2[d * 128 + j];
      snew[idx] += acc;
    }
    __syncthreads();
  }

  for (int idx = tid; idx < 1024; idx += 256) {
    slots_ws[b * 1024 + idx] = snew[idx];
    if (iter == 3) out_slots[b * 1024 + idx] = snew[idx];
  }
  // hq = LN(snew, g_sl, b_sl)
  {
    int wv_ = tid >> 6, lane = tid & 63;
    for (int kk = wv_; kk < 16; kk += 4) {
      float v = snew[kk * 64 + lane];
      float m = wsum64(v) * (1.f / 64.f);
      float dd = v - m;
      float var = wsum64(dd * dd) * (1.f / 64.f);
      hh[kk * 64 + lane] = dd * rsqrtf(var + LN_EPS_) * g_sl[lane] + b_sl[lane];
    }
  }
  __syncthreads();
  // q = hq @ Wq^T + bq
  for (int idx = tid; idx < 1024; idx += 256) {
    int kk = idx >> 6, d = idx & 63;
    float acc = bq[d];
    for (int e = 0; e < 64; ++e) acc += hh[kk * 64 + e] * wq[d * 64 + e];
    qv[idx] = acc;
  }
  __syncthreads();
  // q2 = q @ Wk ;  qc = q . bk
  for (int idx = tid; idx < 1024; idx += 256) {
    int kk = idx >> 6, e = idx & 63;
    float acc = 0.f;
    for (int d = 0; d < 64; ++d) acc += qv[kk * 64 + d] * wk[d * 64 + e];
    q2w[b * 1024 + idx] = acc;
  }
  if (tid < 16) {
    float acc = 0.f;
    for (int d = 0; d < 64; ++d) acc += qv[tid * 64 + d] * bk[d];
    qcw[b * 16 + tid] = acc;
  }
}

extern "C" void kernel_launch(void* const* d_in, const int* in_sizes, int n_in,
                              void* d_out, int out_size, void* d_ws, size_t ws_size,
                              hipStream_t stream) {
  const float* inputs = (const float*)d_in[0];
  // d_in[1] (mask) is mathematically irrelevant: softmax over slots is shift-invariant per (b,n)
  const float* noise  = (const float*)d_in[2];
  const float* mu     = (const float*)d_in[3];
  const float* logvar = (const float*)d_in[4];
  const float* wq   = (const float*)d_in[5];
  const float* bq   = (const float*)d_in[6];
  const float* wk   = (const float*)d_in[7];
  const float* bk   = (const float*)d_in[8];
  const float* wv   = (const float*)d_in[9];
  const float* bv   = (const float*)d_in[10];
  const float* w_ih = (const float*)d_in[11];
  const float* w_hh = (const float*)d_in[12];
  const float* b_ih = (const float*)d_in[13];
  const float* b_hh = (const float*)d_in[14];
  const float* g_in = (const float*)d_in[15];
  const float* b_in = (const float*)d_in[16];
  const float* g_sl = (const float*)d_in[17];
  const float* b_sl = (const float*)d_in[18];
  const float* g_mlp = (const float*)d_in[19];
  const float* b_mlp = (const float*)d_in[20];
  const float* w1 = (const float*)d_in[21];
  const float* b1 = (const float*)d_in[22];
  const float* w2 = (const float*)d_in[23];
  const float* b2 = (const float*)d_in[24];

  float* out_slots = (float*)d_out;
  float* attn_out = out_slots + B_ * K_ * D_;

  float* ws = (float*)d_ws;
  float* slots_ws = ws;                // 262144
  float* q2w = ws + 262144;            // 262144
  float* qcw = ws + 524288;            // 4096
  float* U   = ws + 528384;            // 262144
  float* S   = ws + 790528;            // 4096
  float* xs  = ws + 794624;            // 16384

  dim3 agrid(4, 256), ablock(256);

#define MID(it) mid_kernel<<<256, 256, 0, stream>>>(it, noise, mu, logvar, wq, bq, wk, bk, wv, bv, \
      w_ih, w_hh, b_ih, b_hh, g_sl, b_sl, g_mlp, b_mlp, w1, b1, w2, b2, \
      slots_ws, q2w, qcw, U, S, xs, out_slots)

  MID(0);
  hipMemsetAsync(U, 0, (262144 + 4096 + 16384) * sizeof(float), stream);  // U,S,xs
  attend_kernel<0><<<agrid, ablock, 0, stream>>>(inputs, g_in, b_in, q2w, qcw, U, S, xs, attn_out);
  MID(1);
  hipMemsetAsync(U, 0, (262144 + 4096) * sizeof(float), stream);          // U,S (xs reused)
  attend_kernel<1><<<agrid, ablock, 0, stream>>>(inputs, g_in, b_in, q2w, qcw, U, S, xs, attn_out);
  MID(2);
  hipMemsetAsync(U, 0, (262144 + 4096) * sizeof(float), stream);
  attend_kernel<1><<<agrid, ablock, 0, stream>>>(inputs, g_in, b_in, q2w, qcw, U, S, xs, attn_out);
  MID(3);
  attend_kernel<2><<<agrid, ablock, 0, stream>>>(inputs, g_in, b_in, q2w, qcw, U, S, xs, attn_out);
#undef MID
}

// Round 2
// 787.400 us; speedup vs baseline: 2.0068x; 2.0068x over previous
//
#include <hip/hip_runtime.h>
#include <hip/hip_bf16.h>
#include <stdint.h>

#define B_ 256
#define N_ 4096
#define D_ 64
#define K_ 16
#define EPS_ 1e-8f
#define LN_EPS_ 1e-5f

typedef __attribute__((ext_vector_type(8))) short short8;
typedef __attribute__((ext_vector_type(4))) float f32x4;

__device__ __forceinline__ unsigned short f2bf(float f) {
  unsigned u = __builtin_bit_cast(unsigned, f);
  u += 0x7fffu + ((u >> 16) & 1u);
  return (unsigned short)(u >> 16);
}

__device__ __forceinline__ float sum4(f32x4 x) { return x[0] + x[1] + x[2] + x[3]; }

__device__ __forceinline__ float wsum64(float v) {
  v += __shfl_xor(v, 1); v += __shfl_xor(v, 2); v += __shfl_xor(v, 4);
  v += __shfl_xor(v, 8); v += __shfl_xor(v, 16); v += __shfl_xor(v, 32);
  return v;
}

// MODE 1: accumulate U,S.  MODE 2: final pass, write attn.
// LOADBF: read bf16 LN'd x from xcache.  STORECACHE: write bf16 LN'd x to xcache.
template<int MODE, int LOADBF, int STORECACHE>
__global__ __launch_bounds__(256)
void attend2(const float* __restrict__ inputs,
             unsigned short* __restrict__ xcache,
             const float* __restrict__ g_in, const float* __restrict__ b_in,
             const float* __restrict__ q2w, const float* __restrict__ qcw,
             float* __restrict__ U, float* __restrict__ S,
             float* __restrict__ attn_out)
{
  const int b = blockIdx.y;
  const int chunk = blockIdx.x;
  const int wave = threadIdx.x >> 6;
  const int lane = threadIdx.x & 63;
  const int n = lane & 15;       // A-frag: slot m. B-frag: row/dim n. C: col.
  const int quad = lane >> 4;

  __shared__ unsigned short xbt[4][64][40];   // per-wave x transposed [dim][rowIn32], stride 40 (80B)
  __shared__ unsigned short pbuf[4][16][40];  // per-wave p [slot][rowIn32]
  __shared__ float redS[4][16];

  // ---- q2 A-fragments (q2[slot][dim], slot = lane&15, dims quad*8.. / 32+quad*8..)
  const float* qp = q2w + b * 1024 + n * 64 + quad * 8;
  short8 qa0, qa1;
#pragma unroll
  for (int j = 0; j < 8; ++j) {
    qa0[j] = (short)f2bf(qp[j]);
    qa1[j] = (short)f2bf(qp[32 + j]);
  }
  float qc[4];
#pragma unroll
  for (int r = 0; r < 4; ++r) qc[r] = qcw[b * 16 + quad * 4 + r];

  f32x4 gi[4], bi[4];
  if constexpr (!LOADBF) {
    gi[0] = *(const f32x4*)(g_in + quad * 8);       gi[1] = *(const f32x4*)(g_in + quad * 8 + 4);
    gi[2] = *(const f32x4*)(g_in + 32 + quad * 8);  gi[3] = *(const f32x4*)(g_in + 36 + quad * 8);
    bi[0] = *(const f32x4*)(b_in + quad * 8);       bi[1] = *(const f32x4*)(b_in + quad * 8 + 4);
    bi[2] = *(const f32x4*)(b_in + 32 + quad * 8);  bi[3] = *(const f32x4*)(b_in + 36 + quad * 8);
  }

  f32x4 Uacc[4];
#pragma unroll
  for (int t = 0; t < 4; ++t) Uacc[t] = (f32x4){0.f, 0.f, 0.f, 0.f};
  float Sacc[4] = {0.f, 0.f, 0.f, 0.f};

  const int rowwave = chunk * 1024 + wave * 256;

  for (int g = 0; g < 8; ++g) {
#pragma unroll
    for (int sub = 0; sub < 2; ++sub) {
      const int row = rowwave + g * 32 + sub * 16 + n;
      short8 xlo, xhi;
      if constexpr (LOADBF) {
        const unsigned short* xp = xcache + ((size_t)(b * N_ + row)) * 64 + quad * 8;
        xlo = __builtin_bit_cast(short8, *(const f32x4*)xp);
        xhi = __builtin_bit_cast(short8, *(const f32x4*)(xp + 32));
      } else {
        const float* bp = inputs + ((size_t)(b * N_ + row)) * 64;
        f32x4 a0 = *(const f32x4*)(bp + quad * 8);
        f32x4 a1 = *(const f32x4*)(bp + quad * 8 + 4);
        f32x4 a2 = *(const f32x4*)(bp + 32 + quad * 8);
        f32x4 a3 = *(const f32x4*)(bp + 36 + quad * 8);
        float s = sum4(a0) + sum4(a1) + sum4(a2) + sum4(a3);
        s += __shfl_xor(s, 16); s += __shfl_xor(s, 32);
        const float m = s * (1.f / 64.f);
        f32x4 d0 = a0 - m, d1 = a1 - m, d2 = a2 - m, d3 = a3 - m;
        float v = sum4(d0 * d0) + sum4(d1 * d1) + sum4(d2 * d2) + sum4(d3 * d3);
        v += __shfl_xor(v, 16); v += __shfl_xor(v, 32);
        const float rs = rsqrtf(v * (1.f / 64.f) + LN_EPS_);
        f32x4 y0 = d0 * rs * gi[0] + bi[0];
        f32x4 y1 = d1 * rs * gi[1] + bi[1];
        f32x4 y2 = d2 * rs * gi[2] + bi[2];
        f32x4 y3 = d3 * rs * gi[3] + bi[3];
#pragma unroll
        for (int j = 0; j < 4; ++j) {
          xlo[j]     = (short)f2bf(y0[j]);
          xlo[4 + j] = (short)f2bf(y1[j]);
          xhi[j]     = (short)f2bf(y2[j]);
          xhi[4 + j] = (short)f2bf(y3[j]);
        }
        if constexpr (STORECACHE) {
          unsigned short* sp = xcache + ((size_t)(b * N_ + row)) * 64 + quad * 8;
          *(f32x4*)sp = __builtin_bit_cast(f32x4, xlo);
          *(f32x4*)(sp + 32) = __builtin_bit_cast(f32x4, xhi);
        }
      }

      // ---- QK: logits C-tile = q2 · xln^T   (C[m=slot][n=row])
      f32x4 c = __builtin_amdgcn_mfma_f32_16x16x32_bf16(qa0, xlo, (f32x4){0.f, 0.f, 0.f, 0.f}, 0, 0, 0);
      c = __builtin_amdgcn_mfma_f32_16x16x32_bf16(qa1, xhi, c, 0, 0, 0);

      // ---- softmax over 16 slots (4 regs in-lane + quads via shfl 16/32)
      float l[4];
#pragma unroll
      for (int r = 0; r < 4; ++r) l[r] = (c[r] + qc[r]) * 0.125f;
      float mx = fmaxf(fmaxf(l[0], l[1]), fmaxf(l[2], l[3]));
      mx = fmaxf(mx, __shfl_xor(mx, 16));
      mx = fmaxf(mx, __shfl_xor(mx, 32));
      float e[4], es = 0.f;
#pragma unroll
      for (int r = 0; r < 4; ++r) { e[r] = __expf(l[r] - mx); es += e[r]; }
      es += __shfl_xor(es, 16); es += __shfl_xor(es, 32);
      const float rinv = 1.f / es;

      if constexpr (MODE == 2) {
#pragma unroll
        for (int r = 0; r < 4; ++r)
          attn_out[((size_t)b * 16 + quad * 4 + r) * N_ + row] = e[r] * rinv;
      } else {
#pragma unroll
        for (int r = 0; r < 4; ++r) {
          const float p = e[r] * rinv;
          Sacc[r] += p;
          pbuf[wave][quad * 4 + r][sub * 16 + n] = f2bf(p);
        }
#pragma unroll
        for (int j = 0; j < 8; ++j) {
          xbt[wave][quad * 8 + j][sub * 16 + n]      = (unsigned short)xlo[j];
          xbt[wave][32 + quad * 8 + j][sub * 16 + n] = (unsigned short)xhi[j];
        }
      }
    }

    if constexpr (MODE != 2) {
      // ---- PV: U[slot][dim] += p(16x32) · xln(32x64), 4 dim-tiles
      short8 pa = *(const short8*)&pbuf[wave][n][quad * 8];
#pragma unroll
      for (int t = 0; t < 4; ++t) {
        short8 bx = *(const short8*)&xbt[wave][t * 16 + n][quad * 8];
        Uacc[t] = __builtin_amdgcn_mfma_f32_16x16x32_bf16(pa, bx, Uacc[t], 0, 0, 0);
      }
    }
  }

  if constexpr (MODE == 2) return;

  // ---- S: reduce over rows (n-lanes) via shfl
#pragma unroll
  for (int r = 0; r < 4; ++r) {
    float sv = Sacc[r];
    sv += __shfl_xor(sv, 1); sv += __shfl_xor(sv, 2);
    sv += __shfl_xor(sv, 4); sv += __shfl_xor(sv, 8);
    if (n == 0) redS[wave][quad * 4 + r] = sv;
  }
  __syncthreads();                       // all waves done with xbt → reuse as red
  float* red = (float*)&xbt[0][0][0];    // [16][256] fp32 = 16 KB <= 20.5 KB
#pragma unroll
  for (int t = 0; t < 4; ++t)
#pragma unroll
    for (int r = 0; r < 4; ++r)
      red[(t * 4 + r) * 256 + wave * 64 + lane] = Uacc[t][r];
  __syncthreads();
#pragma unroll
  for (int ii = 0; ii < 4; ++ii) {
    const int i = wave * 4 + ii;
    const float sum = red[i * 256 + lane] + red[i * 256 + 64 + lane] +
                      red[i * 256 + 128 + lane] + red[i * 256 + 192 + lane];
    const int t = i >> 2, r = i & 3;
    atomicAdd(&U[b * 1024 + (quad * 4 + r) * 64 + t * 16 + n], sum);
  }
  if (threadIdx.x < 16) {
    const float ss = redS[0][threadIdx.x] + redS[1][threadIdx.x] +
                     redS[2][threadIdx.x] + redS[3][threadIdx.x];
    atomicAdd(&S[b * 16 + threadIdx.x], ss);
  }
}

// Per-batch slot update (GRU + MLP) and q' recompute. iter==0: init slots from noise.
__global__ __launch_bounds__(256)
void mid_kernel(int iter,
                const float* __restrict__ noise, const float* __restrict__ mu,
                const float* __restrict__ logvar,
                const float* __restrict__ wq, const float* __restrict__ bq,
                const float* __restrict__ wk, const float* __restrict__ bk,
                const float* __restrict__ wv, const float* __restrict__ bv,
                const float* __restrict__ w_ih, const float* __restrict__ w_hh,
                const float* __restrict__ b_ih, const float* __restrict__ b_hh,
                const float* __restrict__ g_sl, const float* __restrict__ b_sl,
                const float* __restrict__ g_mlp, const float* __restrict__ b_mlp,
                const float* __restrict__ w1, const float* __restrict__ b1,
                const float* __restrict__ w2, const float* __restrict__ b2,
                float* __restrict__ slots_ws, float* __restrict__ q2w, float* __restrict__ qcw,
                const float* __restrict__ U, const float* __restrict__ S,
                float* __restrict__ out_slots)
{
  const int b = blockIdx.x;
  const int tid = threadIdx.x;
  __shared__ float sl[1024];
  __shared__ float snew[1024];
  __shared__ float updx[1024];
  __shared__ float upds[1024];
  __shared__ float gx[3072];
  __shared__ float gh[3072];
  __shared__ float hh[1024];
  __shared__ float t1[2048];
  __shared__ float qv[1024];

  if (iter == 0) {
    for (int idx = tid; idx < 1024; idx += 256) {
      int d = idx & 63;
      snew[idx] = mu[d] + expf(0.5f * logvar[d]) * noise[(size_t)b * 1024 + idx];
    }
    __syncthreads();
  } else {
    for (int idx = tid; idx < 1024; idx += 256) sl[idx] = slots_ws[b * 1024 + idx];
    for (int idx = tid; idx < 1024; idx += 256) {
      int kk = idx >> 6;
      float denom = S[b * 16 + kk] + (float)N_ * EPS_;
      updx[idx] = U[b * 1024 + idx] / denom;
    }
    __syncthreads();
    for (int idx = tid; idx < 1024; idx += 256) {
      int kk = idx >> 6, d = idx & 63;
      float acc = bv[d];
      for (int e = 0; e < 64; ++e) acc += updx[kk * 64 + e] * wv[d * 64 + e];
      upds[idx] = acc;
    }
    __syncthreads();
    for (int idx = tid; idx < 3072; idx += 256) {
      int kk = idx / 192, j = idx % 192;
      float ax = b_ih[j], ah = b_hh[j];
      for (int d = 0; d < 64; ++d) {
        ax += upds[kk * 64 + d] * w_ih[j * 64 + d];
        ah += sl[kk * 64 + d] * w_hh[j * 64 + d];
      }
      gx[idx] = ax;
      gh[idx] = ah;
    }
    __syncthreads();
    for (int idx = tid; idx < 1024; idx += 256) {
      int kk = idx >> 6, d = idx & 63;
      float xr_ = gx[kk * 192 + d], xz_ = gx[kk * 192 + 64 + d], xn_ = gx[kk * 192 + 128 + d];
      float hr_ = gh[kk * 192 + d], hz_ = gh[kk * 192 + 64 + d], hn_ = gh[kk * 192 + 128 + d];
      float r_ = 1.f / (1.f + expf(-(xr_ + hr_)));
      float z_ = 1.f / (1.f + expf(-(xz_ + hz_)));
      float n_ = tanhf(xn_ + r_ * hn_);
      snew[idx] = (1.f - z_) * n_ + z_ * sl[idx];
    }
    __syncthreads();
    {
      int wv_ = tid >> 6, lane = tid & 63;
      for (int kk = wv_; kk < 16; kk += 4) {
        float v = snew[kk * 64 + lane];
        float m = wsum64(v) * (1.f / 64.f);
        float dd = v - m;
        float var = wsum64(dd * dd) * (1.f / 64.f);
        hh[kk * 64 + lane] = dd * rsqrtf(var + LN_EPS_) * g_mlp[lane] + b_mlp[lane];
      }
    }
    __syncthreads();
    for (int idx = tid; idx < 2048; idx += 256) {
      int kk = idx >> 7, j = idx & 127;
      float acc = b1[j];
      for (int d = 0; d < 64; ++d) acc += hh[kk * 64 + d] * w1[j * 64 + d];
      t1[idx] = fmaxf(acc, 0.f);
    }
    __syncthreads();
    for (int idx = tid; idx < 1024; idx += 256) {
      int kk = idx >> 6, d = idx & 63;
      float acc = b2[d];
      for (int j = 0; j < 128; ++j) acc += t1[kk * 128 + j] * w2[d * 128 + j];
      snew[idx] += acc;
    }
    __syncthreads();
  }

  for (int idx = tid; idx < 1024; idx += 256) {
    slots_ws[b * 1024 + idx] = snew[idx];
    if (iter == 3) out_slots[b * 1024 + idx] = snew[idx];
  }
  {
    int wv_ = tid >> 6, lane = tid & 63;
    for (int kk = wv_; kk < 16; kk += 4) {
      float v = snew[kk * 64 + lane];
      float m = wsum64(v) * (1.f / 64.f);
      float dd = v - m;
      float var = wsum64(dd * dd) * (1.f / 64.f);
      hh[kk * 64 + lane] = dd * rsqrtf(var + LN_EPS_) * g_sl[lane] + b_sl[lane];
    }
  }
  __syncthreads();
  for (int idx = tid; idx < 1024; idx += 256) {
    int kk = idx >> 6, d = idx & 63;
    float acc = bq[d];
    for (int e = 0; e < 64; ++e) acc += hh[kk * 64 + e] * wq[d * 64 + e];
    qv[idx] = acc;
  }
  __syncthreads();
  for (int idx = tid; idx < 1024; idx += 256) {
    int kk = idx >> 6, e = idx & 63;
    float acc = 0.f;
    for (int d = 0; d < 64; ++d) acc += qv[kk * 64 + d] * wk[d * 64 + e];
    q2w[b * 1024 + idx] = acc;
  }
  if (tid < 16) {
    float acc = 0.f;
    for (int d = 0; d < 64; ++d) acc += qv[tid * 64 + d] * bk[d];
    qcw[b * 16 + tid] = acc;
  }
}

extern "C" void kernel_launch(void* const* d_in, const int* in_sizes, int n_in,
                              void* d_out, int out_size, void* d_ws, size_t ws_size,
                              hipStream_t stream) {
  const float* inputs = (const float*)d_in[0];
  // d_in[1] (mask): softmax over slots is shift-invariant per (b,n) -> irrelevant
  const float* noise  = (const float*)d_in[2];
  const float* mu     = (const float*)d_in[3];
  const float* logvar = (const float*)d_in[4];
  const float* wq   = (const float*)d_in[5];
  const float* bq   = (const float*)d_in[6];
  const float* wk   = (const float*)d_in[7];
  const float* bk   = (const float*)d_in[8];
  const float* wv   = (const float*)d_in[9];
  const float* bv   = (const float*)d_in[10];
  const float* w_ih = (const float*)d_in[11];
  const float* w_hh = (const float*)d_in[12];
  const float* b_ih = (const float*)d_in[13];
  const float* b_hh = (const float*)d_in[14];
  const float* g_in = (const float*)d_in[15];
  const float* b_in = (const float*)d_in[16];
  const float* g_sl = (const float*)d_in[17];
  const float* b_sl = (const float*)d_in[18];
  const float* g_mlp = (const float*)d_in[19];
  const float* b_mlp = (const float*)d_in[20];
  const float* w1 = (const float*)d_in[21];
  const float* b1 = (const float*)d_in[22];
  const float* w2 = (const float*)d_in[23];
  const float* b2 = (const float*)d_in[24];

  float* out_slots = (float*)d_out;
  float* attn_out = out_slots + B_ * K_ * D_;

  float* ws = (float*)d_ws;
  float* slots_ws = ws;                  // 262144 floats
  float* q2w = ws + 262144;              // 262144
  float* qcw = ws + 524288;              // 4096
  float* U   = ws + 528384;              // 262144
  float* S   = ws + 790528;              // 4096
  unsigned short* xcache = (unsigned short*)(ws + 794624);  // 134 MB bf16 LN'd x
  const size_t need = (size_t)794624 * 4 + (size_t)B_ * N_ * D_ * 2;
  const bool cached = ws_size >= need;

  dim3 agrid(4, B_), ablock(256);

#define MID(it) mid_kernel<<<256, 256, 0, stream>>>(it, noise, mu, logvar, wq, bq, wk, bk, wv, bv, \
      w_ih, w_hh, b_ih, b_hh, g_sl, b_sl, g_mlp, b_mlp, w1, b1, w2, b2, \
      slots_ws, q2w, qcw, U, S, out_slots)
#define ATT(M, L, SC) attend2<M, L, SC><<<agrid, ablock, 0, stream>>>(inputs, xcache, g_in, b_in, \
      q2w, qcw, U, S, attn_out)

  MID(0);
  hipMemsetAsync(U, 0, (262144 + 4096) * sizeof(float), stream);
  if (cached) ATT(1, 0, 1); else ATT(1, 0, 0);
  MID(1);
  hipMemsetAsync(U, 0, (262144 + 4096) * sizeof(float), stream);
  if (cached) ATT(1, 1, 0); else ATT(1, 0, 0);
  MID(2);
  hipMemsetAsync(U, 0, (262144 + 4096) * sizeof(float), stream);
  if (cached) ATT(1, 1, 0); else ATT(1, 0, 0);
  MID(3);
  if (cached) ATT(2, 1, 0); else ATT(2, 0, 0);
#undef MID
#undef ATT
}